// Round 1
// baseline (575.164 us; speedup 1.0000x reference)
//
#include <hip/hip_runtime.h>

// SelfAttnPool: B=32, T=4096, F=512, U=512 (fp32 in/out)
//   scores[b,t] = tanh(x[b,t,:]@W + b) @ V   (fused, u never materialized)
//   a = softmax_T(scores); out[b,f] = sum_t a[b,t]*x[b,t,f]
//
// GEMM uses 3-term bf16 split (hi*hi + hi*lo + lo*hi) on MFMA 16x16x32 to get
// ~fp32 score precision (softmax over T is near-argmax; raw bf16 is too noisy).

#define XB 32
#define XT 4096
#define XF 512
#define XU 512
#define ROWS (XB * XT)   // 131072

typedef __attribute__((ext_vector_type(8))) short short8;
typedef __attribute__((ext_vector_type(4))) float f32x4;

__device__ inline void cvt_hilo(float x, unsigned short &h, unsigned short &l) {
  unsigned u = __builtin_bit_cast(unsigned, x);
  h = (unsigned short)(u >> 16);                       // truncated bf16 hi
  float hf = __builtin_bit_cast(float, u & 0xFFFF0000u);
  float lo = x - hf;                                   // exact residual
  l = (unsigned short)(__builtin_bit_cast(unsigned, lo) >> 16); // bf16 lo
}

__device__ inline void async_ld16(const void *g, void *l) {
  __builtin_amdgcn_global_load_lds(
      (const __attribute__((address_space(1))) unsigned int *)g,
      (__attribute__((address_space(3))) unsigned int *)l, 16, 0, 0);
}

__device__ inline float tanh_fast(float z) {
  // tanh(z) = 1 - 2/(e^{2z}+1); inf-safe both directions
  float e = __expf(2.0f * z);
  return 1.0f - 2.0f * __builtin_amdgcn_rcpf(e + 1.0f);
}

// ---- W pre-conversion: fp32 [512f][512u] -> bf16 hi/lo in MFMA-ready layout
//      [kw(16)][n(512)][kg(4)][j(8)]  (k = kw*32 + kg*8 + j)
__global__ void wconv_kernel(const float *__restrict__ W,
                             unsigned short *__restrict__ whi,
                             unsigned short *__restrict__ wlo) {
  int t = blockIdx.x * 256 + threadIdx.x;  // 32768 threads
  int n = t & 511;
  int kg = (t >> 9) & 3;
  int kw = t >> 11;
  int kbase = kw * 32 + kg * 8;
  short8 hv, lv;
#pragma unroll
  for (int j = 0; j < 8; ++j) {
    unsigned short h, l;
    cvt_hilo(W[(size_t)(kbase + j) * XU + n], h, l);
    hv[j] = (short)h;
    lv[j] = (short)l;
  }
  size_t off = (size_t)kw * 16384 + (size_t)n * 32 + (size_t)kg * 8;
  *(short8 *)(whi + off) = hv;
  *(short8 *)(wlo + off) = lv;
}

// ---- fused GEMM + tanh + (.@V) -> scores[ROWS]
// block: 256 thr = 4 waves (2x2), tile 64 rows x 512 cols, BK=32, 16 k-steps.
// W hi/lo staged to LDS via global_load_lds (64 KB); x A-frags loaded directly
// from global per lane (32B contiguous per row) and split hi/lo in registers.
__global__ __launch_bounds__(256, 2)
void gemm_scores_kernel(const float *__restrict__ x,
                        const unsigned short *__restrict__ whi,
                        const unsigned short *__restrict__ wlo,
                        const float *__restrict__ bias,
                        const float *__restrict__ V,
                        float *__restrict__ scores) {
  __shared__ unsigned short wsm[32768];  // 64 KB: [hi|lo][n512][kg4][j8]

  const int tid = threadIdx.x;
  const int lane = tid & 63;
  const int wave = tid >> 6;
  const int wr = wave >> 1;   // row half (32 rows)
  const int wc = wave & 1;    // col half (256 cols)
  const int quad = lane >> 4;
  const int l15 = lane & 15;
  const size_t rowbase = (size_t)blockIdx.x * 64;

  f32x4 acc[2][16];
#pragma unroll
  for (int a = 0; a < 2; ++a)
#pragma unroll
    for (int c = 0; c < 16; ++c) acc[a][c] = (f32x4){0.f, 0.f, 0.f, 0.f};

  const float *xr0 = x + (rowbase + (size_t)wr * 32 + l15) * XF + quad * 8;
  const float *xr1 = xr0 + 16 * XF;
  const int cg0 = wave * 16;

#pragma unroll 1
  for (int kw = 0; kw < 16; ++kw) {
    // stage this k-slice of W (hi+lo = 64 chunks x 1KB); this wave: 16 chunks
#pragma unroll
    for (int i = 0; i < 16; ++i) {
      int cg = cg0 + i;
      int var = cg >> 5;   // 0 = hi, 1 = lo
      int c = cg & 31;
      const unsigned short *g =
          (var ? wlo : whi) + (size_t)kw * 16384 + c * 512 + lane * 8;
      unsigned short *lp = wsm + var * 16384 + c * 512 + lane * 8;
      async_ld16(g, lp);
    }
    // x fragments: 8 contiguous k per lane per row-frag (2 x float4 each)
    const float *p0 = xr0 + kw * 32;
    const float *p1 = xr1 + kw * 32;
    float4 a00 = *(const float4 *)(p0);
    float4 a01 = *(const float4 *)(p0 + 4);
    float4 a10 = *(const float4 *)(p1);
    float4 a11 = *(const float4 *)(p1 + 4);

    __syncthreads();  // W in LDS ready (barrier drains vmcnt incl. x loads)

    short8 ah0, al0, ah1, al1;
    {
      float v0[8] = {a00.x, a00.y, a00.z, a00.w, a01.x, a01.y, a01.z, a01.w};
      float v1[8] = {a10.x, a10.y, a10.z, a10.w, a11.x, a11.y, a11.z, a11.w};
#pragma unroll
      for (int j = 0; j < 8; ++j) {
        unsigned short h, l;
        cvt_hilo(v0[j], h, l);
        ah0[j] = (short)h; al0[j] = (short)l;
        cvt_hilo(v1[j], h, l);
        ah1[j] = (short)h; al1[j] = (short)l;
      }
    }

#pragma unroll
    for (int cf = 0; cf < 16; ++cf) {
      const unsigned short *bp =
          wsm + ((wc * 256 + cf * 16 + l15) * 4 + quad) * 8;
      short8 bh = *(const short8 *)bp;
      short8 bl = *(const short8 *)(bp + 16384);
      acc[0][cf] = __builtin_amdgcn_mfma_f32_16x16x32_bf16(ah0, bh, acc[0][cf], 0, 0, 0);
      acc[1][cf] = __builtin_amdgcn_mfma_f32_16x16x32_bf16(ah1, bh, acc[1][cf], 0, 0, 0);
      acc[0][cf] = __builtin_amdgcn_mfma_f32_16x16x32_bf16(al0, bh, acc[0][cf], 0, 0, 0);
      acc[1][cf] = __builtin_amdgcn_mfma_f32_16x16x32_bf16(al1, bh, acc[1][cf], 0, 0, 0);
      acc[0][cf] = __builtin_amdgcn_mfma_f32_16x16x32_bf16(ah0, bl, acc[0][cf], 0, 0, 0);
      acc[1][cf] = __builtin_amdgcn_mfma_f32_16x16x32_bf16(ah1, bl, acc[1][cf], 0, 0, 0);
    }
    __syncthreads();  // all LDS reads done before restage
  }

  // epilogue: score contribution = sum_n tanh(acc + b[n]) * V[n]
  // C/D layout: col n = l15 (+16*cf+256*wc), row = quad*4 + r (+16*rf+32*wr)
  float sc0[4] = {0.f, 0.f, 0.f, 0.f};
  float sc1[4] = {0.f, 0.f, 0.f, 0.f};
#pragma unroll
  for (int cf = 0; cf < 16; ++cf) {
    int n = wc * 256 + cf * 16 + l15;
    float vv = V[n];
    float bb = bias[n];
#pragma unroll
    for (int r = 0; r < 4; ++r) {
      sc0[r] += tanh_fast(acc[0][cf][r] + bb) * vv;
      sc1[r] += tanh_fast(acc[1][cf][r] + bb) * vv;
    }
  }
  // reduce over the 16 lanes (l15) sharing a quad
#pragma unroll
  for (int m = 1; m <= 8; m <<= 1) {
#pragma unroll
    for (int r = 0; r < 4; ++r) {
      sc0[r] += __shfl_xor(sc0[r], m, 64);
      sc1[r] += __shfl_xor(sc1[r], m, 64);
    }
  }
  // combine the two column-half waves via LDS (wsm is dead now)
  float *scb = (float *)wsm;
  if (l15 == 0) {
    int base = wc * 64 + wr * 32 + quad * 4;
#pragma unroll
    for (int r = 0; r < 4; ++r) {
      scb[base + r] = sc0[r];
      scb[base + 16 + r] = sc1[r];
    }
  }
  __syncthreads();
  if (tid < 64) scores[rowbase + tid] = scb[tid] + scb[64 + tid];
}

// ---- per-batch softmax stats (max, sumexp) over T=4096
__global__ void stats_kernel(const float *__restrict__ scores,
                             float *__restrict__ stats) {
  int b = blockIdx.x, tid = threadIdx.x;
  const float *s = scores + (size_t)b * XT;
  float v[16];
#pragma unroll
  for (int i = 0; i < 16; ++i) v[i] = s[tid + i * 256];
  float mx = v[0];
#pragma unroll
  for (int i = 1; i < 16; ++i) mx = fmaxf(mx, v[i]);
  for (int m = 1; m < 64; m <<= 1) mx = fmaxf(mx, __shfl_xor(mx, m, 64));
  __shared__ float redm[4], reds[4];
  if ((tid & 63) == 0) redm[tid >> 6] = mx;
  __syncthreads();
  mx = fmaxf(fmaxf(redm[0], redm[1]), fmaxf(redm[2], redm[3]));
  float sum = 0.f;
#pragma unroll
  for (int i = 0; i < 16; ++i) sum += __expf(v[i] - mx);
  for (int m = 1; m < 64; m <<= 1) sum += __shfl_xor(sum, m, 64);
  if ((tid & 63) == 0) reds[tid >> 6] = sum;
  __syncthreads();
  if (tid == 0) {
    stats[b * 2] = mx;
    stats[b * 2 + 1] = reds[0] + reds[1] + reds[2] + reds[3];
  }
}

// ---- weighted pooling: out[b,f] += sum_t w[t]*x[b,t,f]; 512 blocks
__global__ __launch_bounds__(256)
void pool_kernel(const float *__restrict__ x, const float *__restrict__ scores,
                 const float *__restrict__ stats, float *__restrict__ out) {
  int b = blockIdx.x >> 4;
  int ch = blockIdx.x & 15;
  int tid = threadIdx.x;
  __shared__ float w[256];
  float mx = stats[b * 2];
  float inv = 1.0f / stats[b * 2 + 1];
  int t0 = ch * 256;
  w[tid] = __expf(scores[(size_t)b * XT + t0 + tid] - mx) * inv;
  __syncthreads();
  const float *xp = x + ((size_t)b * XT + t0) * XF;
  float a0 = 0.f, a1 = 0.f;
#pragma unroll 4
  for (int t = 0; t < 256; ++t) {
    float wv = w[t];
    a0 += wv * xp[(size_t)t * XF + tid];
    a1 += wv * xp[(size_t)t * XF + tid + 256];
  }
  atomicAdd(&out[b * XF + tid], a0);
  atomicAdd(&out[b * XF + tid + 256], a1);
}

extern "C" void kernel_launch(void *const *d_in, const int *in_sizes, int n_in,
                              void *d_out, int out_size, void *d_ws,
                              size_t ws_size, hipStream_t stream) {
  const float *x = (const float *)d_in[0];
  const float *W = (const float *)d_in[1];
  const float *bias = (const float *)d_in[2];
  const float *V = (const float *)d_in[3];
  float *out = (float *)d_out;

  // workspace: whi 512KB | wlo 512KB | scores 512KB | stats 256B
  unsigned short *whi = (unsigned short *)d_ws;
  unsigned short *wlo = whi + 262144;
  float *scores = (float *)((char *)d_ws + 1048576);
  float *stats = (float *)((char *)d_ws + 1572864);

  hipMemsetAsync(d_out, 0, (size_t)out_size * sizeof(float), stream);
  wconv_kernel<<<128, 256, 0, stream>>>(W, whi, wlo);
  gemm_scores_kernel<<<2048, 256, 0, stream>>>(x, whi, wlo, bias, V, scores);
  stats_kernel<<<32, 256, 0, stream>>>(scores, stats);
  pool_kernel<<<512, 256, 0, stream>>>(x, scores, stats, out);
}

// Round 2
// 572.851 us; speedup vs baseline: 1.0040x; 1.0040x over previous
//
#include <hip/hip_runtime.h>

// SelfAttnPool: B=32, T=4096, F=512, U=512 (fp32 in/out)
//   scores[b,t] = tanh(x[b,t,:]@W + b) @ V   (u never materialized)
//   a = softmax_T(scores); out[b,f] = sum_t a[b,t]*x[b,t,f]
//
// R2: barrier-free GEMM K-loop (no LDS staging; W is L2-hot, read as
// pre-permuted MFMA fragments directly from global), mfma 32x32x16 bf16,
// 3-term split (hh + lh + hl) for fp32-grade score precision.
// Pool pass vectorized float4 + 4 blocks/CU.

#define XT 4096
#define XF 512
#define XU 512
#define ROWS (32 * 4096)

typedef __attribute__((ext_vector_type(8))) short short8;
typedef __attribute__((ext_vector_type(16))) float f32x16;

__device__ inline void cvt_hilo(float x, unsigned short &h, unsigned short &l) {
  unsigned u = __builtin_bit_cast(unsigned, x);
  h = (unsigned short)(u >> 16);                       // truncated bf16 hi
  float hf = __builtin_bit_cast(float, u & 0xFFFF0000u);
  float lo = x - hf;                                   // exact residual
  l = (unsigned short)(__builtin_bit_cast(unsigned, lo) >> 16); // bf16 lo
}

__device__ inline float tanh_fast(float z) {
  float e = __expf(2.0f * z);
  return 1.0f - 2.0f * __builtin_amdgcn_rcpf(e + 1.0f);
}

// ---- W pre-conversion: fp32 [512 k][512 n] -> bf16 hi/lo, fragment-ready:
// whi/wlo: [slice s(32)][chunk16B: t(16)*64 + g(2)*32 + l(32)][j(8)]
// element = W[k = s*16 + g*8 + j][n = t*32 + l]
// gemm lane reads chunk (t*64 + lane) -> 64 lanes read 1KB contiguous.
__global__ void wconv_kernel(const float *__restrict__ W,
                             unsigned short *__restrict__ whi,
                             unsigned short *__restrict__ wlo) {
  int t2 = blockIdx.x * 256 + threadIdx.x;  // 32768 threads
  int l = t2 & 31;
  int g = (t2 >> 5) & 1;
  int t = (t2 >> 6) & 15;
  int s = t2 >> 10;
  short8 hv, lv;
#pragma unroll
  for (int j = 0; j < 8; ++j) {
    unsigned short h, lo;
    cvt_hilo(W[(size_t)(s * 16 + g * 8 + j) * XU + t * 32 + l], h, lo);
    hv[j] = (short)h;
    lv[j] = (short)lo;
  }
  size_t off = (size_t)s * 8192 + t * 512 + g * 256 + l * 8;
  *(short8 *)(whi + off) = hv;
  *(short8 *)(wlo + off) = lv;
}

// ---- fused GEMM + tanh + (.@V) -> scores[ROWS]
// block: 512 thr = 8 waves; tile 128 rows x 512 cols.
// wave (wr=w>>2, wc=w&3): 64 rows (2 frags of 32) x 128 cols (4 tiles of 32).
// NO barriers in K-loop: B-frags from global (L2-hot 1MB), A from global
// (L1-hot per block). acc[2][4] of f32x16 = 128 VGPRs.
__global__ __launch_bounds__(512, 2)
void gemm_scores_kernel(const float *__restrict__ x,
                        const unsigned short *__restrict__ whi,
                        const unsigned short *__restrict__ wlo,
                        const float *__restrict__ bias,
                        const float *__restrict__ V,
                        float *__restrict__ scores) {
  __shared__ float scb[512];  // [wc(4)][row(128)] partial scores

  const int tid = threadIdx.x;
  const int lane = tid & 63;
  const int wave = tid >> 6;
  const int wr = wave >> 2;   // row half (64 rows)
  const int wc = wave & 3;    // col quarter (128 cols)
  const int l31 = lane & 31;
  const int half = lane >> 5;
  const size_t rowbase = (size_t)blockIdx.x * 128;

  f32x16 acc[2][4];
#pragma unroll
  for (int a = 0; a < 2; ++a)
#pragma unroll
    for (int c = 0; c < 4; ++c)
#pragma unroll
      for (int r = 0; r < 16; ++r) acc[a][c][r] = 0.f;

  // A: row = rowbase + wr*64 + rf*32 + l31 ; k = s*16 + half*8 + j
  const float *xr0 = x + (rowbase + wr * 64 + l31) * XF + half * 8;
  const float *xr1 = xr0 + 32 * XF;
  // B: chunk base for this wave's col tiles (ntile = wc*4 + cf)
  const unsigned short *whp = whi + (size_t)(wc * 4) * 512 + lane * 8;
  const unsigned short *wlp = wlo + (size_t)(wc * 4) * 512 + lane * 8;

#pragma unroll 1
  for (int s = 0; s < 32; ++s) {
    short8 bh[4], bl[4];
    const unsigned short *p = whp + (size_t)s * 8192;
    const unsigned short *q = wlp + (size_t)s * 8192;
#pragma unroll
    for (int cf = 0; cf < 4; ++cf) {
      bh[cf] = *(const short8 *)(p + cf * 512);
      bl[cf] = *(const short8 *)(q + cf * 512);
    }
    float4 a00 = *(const float4 *)(xr0 + s * 16);
    float4 a01 = *(const float4 *)(xr0 + s * 16 + 4);
    float4 a10 = *(const float4 *)(xr1 + s * 16);
    float4 a11 = *(const float4 *)(xr1 + s * 16 + 4);

    short8 ah0, al0, ah1, al1;
    {
      float v0[8] = {a00.x, a00.y, a00.z, a00.w, a01.x, a01.y, a01.z, a01.w};
      float v1[8] = {a10.x, a10.y, a10.z, a10.w, a11.x, a11.y, a11.z, a11.w};
#pragma unroll
      for (int j = 0; j < 8; ++j) {
        unsigned short h, lo;
        cvt_hilo(v0[j], h, lo);
        ah0[j] = (short)h; al0[j] = (short)lo;
        cvt_hilo(v1[j], h, lo);
        ah1[j] = (short)h; al1[j] = (short)lo;
      }
    }

#pragma unroll
    for (int cf = 0; cf < 4; ++cf) {
      acc[0][cf] = __builtin_amdgcn_mfma_f32_32x32x16_bf16(ah0, bh[cf], acc[0][cf], 0, 0, 0);
      acc[1][cf] = __builtin_amdgcn_mfma_f32_32x32x16_bf16(ah1, bh[cf], acc[1][cf], 0, 0, 0);
      acc[0][cf] = __builtin_amdgcn_mfma_f32_32x32x16_bf16(al0, bh[cf], acc[0][cf], 0, 0, 0);
      acc[1][cf] = __builtin_amdgcn_mfma_f32_32x32x16_bf16(al1, bh[cf], acc[1][cf], 0, 0, 0);
      acc[0][cf] = __builtin_amdgcn_mfma_f32_32x32x16_bf16(ah0, bl[cf], acc[0][cf], 0, 0, 0);
      acc[1][cf] = __builtin_amdgcn_mfma_f32_32x32x16_bf16(ah1, bl[cf], acc[1][cf], 0, 0, 0);
    }
  }

  // epilogue: sc[row] = sum_n tanh(acc + b[n]) * V[n]
  // C/D 32x32: col n = l31 (+32*cf+128*wc); row = (reg&3)+8*(reg>>2)+4*half (+32*rf+64*wr)
  float sc[2][16];
#pragma unroll
  for (int rf = 0; rf < 2; ++rf)
#pragma unroll
    for (int r = 0; r < 16; ++r) sc[rf][r] = 0.f;

#pragma unroll
  for (int cf = 0; cf < 4; ++cf) {
    int n = wc * 128 + cf * 32 + l31;
    float vv = V[n];
    float bb = bias[n];
#pragma unroll
    for (int rf = 0; rf < 2; ++rf)
#pragma unroll
      for (int r = 0; r < 16; ++r)
        sc[rf][r] += tanh_fast(acc[rf][cf][r] + bb) * vv;
  }
  // reduce across the 32 n-lanes (same half holds same rows)
#pragma unroll
  for (int m = 1; m <= 16; m <<= 1) {
#pragma unroll
    for (int rf = 0; rf < 2; ++rf)
#pragma unroll
      for (int r = 0; r < 16; ++r)
        sc[rf][r] += __shfl_xor(sc[rf][r], m, 64);
  }
  if (l31 == 0) {
#pragma unroll
    for (int rf = 0; rf < 2; ++rf)
#pragma unroll
      for (int r = 0; r < 16; ++r) {
        int row = wr * 64 + rf * 32 + (r & 3) + 8 * (r >> 2) + 4 * half;
        scb[wc * 128 + row] = sc[rf][r];
      }
  }
  __syncthreads();
  if (tid < 128)
    scores[rowbase + tid] =
        scb[tid] + scb[128 + tid] + scb[256 + tid] + scb[384 + tid];
}

// ---- per-batch softmax stats (max, sumexp) over T=4096
__global__ void stats_kernel(const float *__restrict__ scores,
                             float *__restrict__ stats) {
  int b = blockIdx.x, tid = threadIdx.x;
  const float *s = scores + (size_t)b * XT;
  float v[16];
#pragma unroll
  for (int i = 0; i < 16; ++i) v[i] = s[tid + i * 256];
  float mx = v[0];
#pragma unroll
  for (int i = 1; i < 16; ++i) mx = fmaxf(mx, v[i]);
  for (int m = 1; m < 64; m <<= 1) mx = fmaxf(mx, __shfl_xor(mx, m, 64));
  __shared__ float redm[4], reds[4];
  if ((tid & 63) == 0) redm[tid >> 6] = mx;
  __syncthreads();
  mx = fmaxf(fmaxf(redm[0], redm[1]), fmaxf(redm[2], redm[3]));
  float sum = 0.f;
#pragma unroll
  for (int i = 0; i < 16; ++i) sum += __expf(v[i] - mx);
  for (int m = 1; m < 64; m <<= 1) sum += __shfl_xor(sum, m, 64);
  if ((tid & 63) == 0) reds[tid >> 6] = sum;
  __syncthreads();
  if (tid == 0) {
    stats[b * 2] = mx;
    stats[b * 2 + 1] = reds[0] + reds[1] + reds[2] + reds[3];
  }
}

// ---- weighted pooling: out[b,f] += sum_t w[t]*x[b,t,f]
// 1024 blocks (32 batches x 32 chunks of 128 rows); float4 loads.
__global__ __launch_bounds__(256)
void pool_kernel(const float *__restrict__ x, const float *__restrict__ scores,
                 const float *__restrict__ stats, float *__restrict__ out) {
  int b = blockIdx.x >> 5;
  int ch = blockIdx.x & 31;
  int tid = threadIdx.x;
  __shared__ float w[128];
  __shared__ float red[512];
  float mx = stats[b * 2];
  float inv = 1.0f / stats[b * 2 + 1];
  if (tid < 128)
    w[tid] = __expf(scores[(size_t)b * XT + ch * 128 + tid] - mx) * inv;
  __syncthreads();
  int c = tid & 127;   // float4 column
  int ro = tid >> 7;   // row offset 0/1
  const float *xp = x + ((size_t)b * XT + ch * 128) * XF;
  float4 a = {0.f, 0.f, 0.f, 0.f};
#pragma unroll 4
  for (int i = 0; i < 64; ++i) {
    int r = i * 2 + ro;
    float4 v = *(const float4 *)(xp + (size_t)r * XF + c * 4);
    float wv = w[r];
    a.x += wv * v.x;
    a.y += wv * v.y;
    a.z += wv * v.z;
    a.w += wv * v.w;
  }
  if (ro == 1) {
    red[c * 4 + 0] = a.x;
    red[c * 4 + 1] = a.y;
    red[c * 4 + 2] = a.z;
    red[c * 4 + 3] = a.w;
  }
  __syncthreads();
  if (ro == 0) {
    atomicAdd(&out[b * XF + c * 4 + 0], a.x + red[c * 4 + 0]);
    atomicAdd(&out[b * XF + c * 4 + 1], a.y + red[c * 4 + 1]);
    atomicAdd(&out[b * XF + c * 4 + 2], a.z + red[c * 4 + 2]);
    atomicAdd(&out[b * XF + c * 4 + 3], a.w + red[c * 4 + 3]);
  }
}

extern "C" void kernel_launch(void *const *d_in, const int *in_sizes, int n_in,
                              void *d_out, int out_size, void *d_ws,
                              size_t ws_size, hipStream_t stream) {
  const float *x = (const float *)d_in[0];
  const float *W = (const float *)d_in[1];
  const float *bias = (const float *)d_in[2];
  const float *V = (const float *)d_in[3];
  float *out = (float *)d_out;

  // workspace: whi 512KB | wlo 512KB | scores 512KB | stats 256B
  unsigned short *whi = (unsigned short *)d_ws;
  unsigned short *wlo = whi + 262144;
  float *scores = (float *)((char *)d_ws + 1048576);
  float *stats = (float *)((char *)d_ws + 1572864);

  hipMemsetAsync(d_out, 0, (size_t)out_size * sizeof(float), stream);
  wconv_kernel<<<128, 256, 0, stream>>>(W, whi, wlo);
  gemm_scores_kernel<<<1024, 512, 0, stream>>>(x, whi, wlo, bias, V, scores);
  stats_kernel<<<32, 256, 0, stream>>>(scores, stats);
  pool_kernel<<<1024, 256, 0, stream>>>(x, scores, stats, out);
}